// Round 4
// baseline (290.822 us; speedup 1.0000x reference)
//
#include <hip/hip_runtime.h>
#include <hip/hip_bf16.h>

#define DIM 384
#define HEADS 6
#define HD 64
#define HIDDEN 1536
#define SEQ 4096
#define BATCH 2
#define NTOK (BATCH*SEQ)   // 8192
#define QKVN (3*DIM)       // 1152

typedef __attribute__((ext_vector_type(4))) float f32x4;
typedef __attribute__((ext_vector_type(16))) float f32x16;
typedef __attribute__((ext_vector_type(8))) short s16x8;
typedef __attribute__((ext_vector_type(4))) unsigned int u32x4;

__device__ __forceinline__ ushort f2bf(float f) {
    union { float f; unsigned u; } v; v.f = f;
    unsigned r = v.u + 0x7FFF + ((v.u >> 16) & 1);
    return (ushort)(r >> 16);
}
__device__ __forceinline__ float bf2f(ushort b) {
    union { unsigned u; float f; } v; v.u = ((unsigned)b) << 16;
    return v.f;
}
__device__ __forceinline__ unsigned cvtpk(float lo, float hi) {
    unsigned r;
    asm("v_cvt_pk_bf16_f32 %0, %1, %2" : "=v"(r) : "v"(lo), "v"(hi));
    return r;
}
__device__ __forceinline__ void pl32swap(unsigned& a, unsigned& b) {
    asm volatile("v_permlane32_swap_b32 %0, %1" : "+v"(a), "+v"(b));
}
__device__ __forceinline__ void g2l(const ushort* g, ushort* s) {
    __builtin_amdgcn_global_load_lds((const __attribute__((address_space(1))) void*)g,
                                     (__attribute__((address_space(3))) void*)s, 16, 0, 0);
}

// ---------------- merged weight f32 -> bf16 ----------------
__global__ void cvt4_kernel(const float4* __restrict__ s0, ushort* __restrict__ d0, int n0,
                            const float4* __restrict__ s1, ushort* __restrict__ d1, int n1,
                            const float4* __restrict__ s2, ushort* __restrict__ d2, int n2,
                            const float4* __restrict__ s3, ushort* __restrict__ d3, int n3) {
    int i = blockIdx.x * 256 + threadIdx.x;
    const float4* s; ushort* d; int k = i;
    if (i < n0) { s = s0; d = d0; }
    else { k -= n0; if (k < n1) { s = s1; d = d1; }
        else { k -= n1; if (k < n2) { s = s2; d = d2; }
            else { k -= n2; if (k >= n3) return; s = s3; d = d3; } } }
    float4 v = s[k];
    ushort4 o; o.x = f2bf(v.x); o.y = f2bf(v.y); o.z = f2bf(v.z); o.w = f2bf(v.w);
    *(ushort4*)(d + (size_t)k * 4) = o;
}

// ---------------- LayerNorm (wave per row, 384 cols) ----------------
__global__ __launch_bounds__(256) void ln_kernel(const float* __restrict__ x,
        const float* __restrict__ w, const float* __restrict__ b,
        ushort* __restrict__ y) {
    int l = threadIdx.x & 63;
    int row = blockIdx.x * 4 + (threadIdx.x >> 6);
    const float* xr = x + (size_t)row * DIM;
    float v[6], s = 0.f, s2 = 0.f;
#pragma unroll
    for (int i = 0; i < 6; ++i) { v[i] = xr[l + 64*i]; s += v[i]; s2 += v[i]*v[i]; }
#pragma unroll
    for (int d = 1; d < 64; d <<= 1) { s += __shfl_xor(s, d); s2 += __shfl_xor(s2, d); }
    float mean = s * (1.f/DIM);
    float var  = s2 * (1.f/DIM) - mean*mean;
    float rstd = rsqrtf(var + 1e-5f);
    ushort* yr = y + (size_t)row * DIM;
#pragma unroll
    for (int i = 0; i < 6; ++i) {
        int c = l + 64*i;
        yr[c] = f2bf((v[i]-mean)*rstd*w[c] + b[c]);
    }
}

// ---------------- GEMM, 2-phase double-buffered: C = A[M][K] @ W[N][K]^T ----------------
template<int EPI, int BN>
__global__ __launch_bounds__(256) void gemm_kernel(
        const ushort* __restrict__ A, const ushort* __restrict__ W,
        const float* __restrict__ bias, const float* __restrict__ resid,
        void* __restrict__ Cout, int M, int N, int K) {
    __shared__ __align__(16) ushort lds_a[2][128*32];
    __shared__ __align__(16) ushort lds_b[2][BN*32];
    const int t = threadIdx.x, l = t & 63, wid = t >> 6;
    const int lo = l & 15, lg = l >> 4;
    const int m0 = blockIdx.x * 128, n0 = blockIdx.y * BN;
    constexpr int MI = (BN == 128) ? 4 : 2;
    const int wrow = (BN == 128) ? (wid >> 1) * 64 : wid * 32;
    const int wcol = (BN == 128) ? (wid & 1) * 64 : 0;
    f32x4 acc[MI][4] = {};
    const int srow = l >> 2, scol = (l & 3) * 8;
    const ushort* gA0 = A + (size_t)(m0 + wid*16 + srow) * K + scol;
    const ushort* gA1 = A + (size_t)(m0 + (wid+4)*16 + srow) * K + scol;
    const ushort* gB0 = W + (size_t)(n0 + wid*16 + srow) * K + scol;
    const ushort* gB1 = W + (size_t)(n0 + (wid+4)*16 + srow) * K + scol; // BN=128 only

#define STAGE(BUF, K0) do {                                               \
    g2l(gA0 + (K0), &lds_a[BUF][wid * 512]);                              \
    g2l(gA1 + (K0), &lds_a[BUF][(wid + 4) * 512]);                        \
    g2l(gB0 + (K0), &lds_b[BUF][wid * 512]);                              \
    if constexpr (BN == 128) g2l(gB1 + (K0), &lds_b[BUF][(wid + 4) * 512]);\
} while (0)

#define COMPUTE(BUF) do {                                                 \
    s16x8 af[MI], bfr[4];                                                 \
    _Pragma("unroll")                                                     \
    for (int mi = 0; mi < MI; ++mi)                                       \
        af[mi] = *(const s16x8*)&lds_a[BUF][(wrow + mi*16 + lo)*32 + lg*8];\
    _Pragma("unroll")                                                     \
    for (int ni = 0; ni < 4; ++ni)                                        \
        bfr[ni] = *(const s16x8*)&lds_b[BUF][(wcol + ni*16 + lo)*32 + lg*8];\
    _Pragma("unroll")                                                     \
    for (int mi = 0; mi < MI; ++mi)                                       \
        _Pragma("unroll")                                                 \
        for (int ni = 0; ni < 4; ++ni)                                    \
            acc[mi][ni] = __builtin_amdgcn_mfma_f32_16x16x32_bf16(af[mi], bfr[ni], acc[mi][ni], 0,0,0);\
} while (0)

    const int NT = K / 32;   // always even here (12 or 48)
    STAGE(0, 0);
    asm volatile("s_waitcnt vmcnt(0)");
    __syncthreads();
    for (int tt = 0; tt < NT; tt += 2) {
        if (tt + 1 < NT) STAGE(1, (tt + 1) * 32);
        COMPUTE(0);
        asm volatile("s_waitcnt vmcnt(0)");
        __syncthreads();
        if (tt + 2 < NT) STAGE(0, (tt + 2) * 32);
        COMPUTE(1);
        if (tt + 2 < NT) {
            asm volatile("s_waitcnt vmcnt(0)");
            __syncthreads();
        }
    }
#undef STAGE
#undef COMPUTE

#pragma unroll
    for (int mi = 0; mi < MI; ++mi)
#pragma unroll
    for (int ni = 0; ni < 4; ++ni)
#pragma unroll
    for (int r = 0; r < 4; ++r) {
        int row = m0 + wrow + mi*16 + lg*4 + r;
        int col = n0 + wcol + ni*16 + lo;
        float c = acc[mi][ni][r];
        size_t idx = (size_t)row * N + col;
        if (EPI == 0) {
            ((ushort*)Cout)[idx] = f2bf(c);
        } else if (EPI == 1) {
            ((float*)Cout)[idx] = c + bias[col] + resid[idx];
        } else if (EPI == 2) {
            c += bias[col];
            ((ushort*)Cout)[idx] = f2bf(0.5f * c * (1.f + erff(c * 0.70710678118f)));
        } else {
            ((float*)Cout)[idx] = 2.f * (c + bias[col]);
        }
    }
}

// ---------------- Flash attention: max-free exp2 softmax, permlane P exchange ----------------
#define PV_STEP(S, MM, CB) do {                                                   \
    unsigned w0 = cvtpk(S[8*MM+0], S[8*MM+1]);                                    \
    unsigned w1 = cvtpk(S[8*MM+2], S[8*MM+3]);                                    \
    unsigned w2 = cvtpk(S[8*MM+4], S[8*MM+5]);                                    \
    unsigned w3 = cvtpk(S[8*MM+6], S[8*MM+7]);                                    \
    pl32swap(w0, w2); pl32swap(w1, w3);                                           \
    u32x4 fw = {w0, w1, w2, w3};                                                  \
    s16x8 pa = __builtin_bit_cast(s16x8, fw);                                     \
    int colb = ((CB) + G*8) ^ swz0;                                               \
    s16x8 vb0 = *(const s16x8*)&lds_v[half][q31][colb];                           \
    s16x8 vb1 = *(const s16x8*)&lds_v[half][32 + q31][colb ^ 32];                 \
    o0 = __builtin_amdgcn_mfma_f32_32x32x16_bf16(pa, vb0, o0, 0,0,0);             \
    o1 = __builtin_amdgcn_mfma_f32_32x32x16_bf16(pa, vb1, o1, 0,0,0);             \
} while (0)

__global__ __launch_bounds__(256, 3) void attn_kernel(const ushort* __restrict__ qkv,
                                                      ushort* __restrict__ out) {
    __shared__ __align__(16) ushort lds_k[2][64][72];
    __shared__ __align__(16) ushort lds_v[2][64][72];
    const int t = threadIdx.x, l = t & 63, wid = t >> 6;
    const int G = l >> 5, q31 = l & 31, half = wid >> 1;
    const int b = blockIdx.y / HEADS, h = blockIdx.y % HEADS;
    const ushort* base = qkv + (size_t)b * SEQ * QKVN + h * HD;
    const int q0 = blockIdx.x * 64 + (wid & 1) * 32;

    // Q fragments pre-scaled by 0.125*log2(e) (exp2 domain)
    const float QSC = 0.1803368801111137f;
    s16x8 qf[4];
#pragma unroll
    for (int dc = 0; dc < 4; ++dc) {
        s16x8 qv = *(const s16x8*)(base + (size_t)(q0 + q31) * QKVN + dc*16 + G*8);
#pragma unroll
        for (int j = 0; j < 8; ++j)
            qv[j] = (short)f2bf(bf2f((ushort)qv[j]) * QSC);
        qf[dc] = qv;
    }

    f32x16 o0 = {}, o1 = {};
    float l_run = 0.f;

    const int u = t & 127, sa = u >> 3, sc = u & 7;
    const ushort* kbase = base + DIM;
    const ushort* vbase = base + 2*DIM;
    const int key0base = half * (SEQ/2);
    const int swz0 = ((q31 >> 3) & 3) << 3;

    // prologue: tile 0 of K and V into regs
    s16x8 kreg[4], vreg[4];
#pragma unroll
    for (int p = 0; p < 4; ++p) {
        kreg[p] = *(const s16x8*)(kbase + (size_t)(key0base + p*16 + sa) * QKVN + sc*8);
        vreg[p] = *(const s16x8*)(vbase + (size_t)(key0base + p*16 + sa) * QKVN + sc*8);
    }

    for (int it = 0; it < 32; ++it) {
        const int key0 = key0base + it*64;
        __syncthreads();   // previous compute done; LDS writable
#pragma unroll
        for (int p = 0; p < 4; ++p) {
            *(s16x8*)&lds_k[half][p*16 + sa][sc*8] = kreg[p];
            const int colp = (p*16 + sa) ^ ((sc & 3) << 3) ^ ((sc >> 2) << 5);
#pragma unroll
            for (int j = 0; j < 8; ++j)
                lds_v[half][sc*8 + j][colp] = (ushort)vreg[p][j];
        }
        __syncthreads();
        if (it < 31) {     // prefetch next K+V tiles into regs; latency hides under compute
#pragma unroll
            for (int p = 0; p < 4; ++p) {
                kreg[p] = *(const s16x8*)(kbase + (size_t)(key0 + 64 + p*16 + sa) * QKVN + sc*8);
                vreg[p] = *(const s16x8*)(vbase + (size_t)(key0 + 64 + p*16 + sa) * QKVN + sc*8);
            }
        }

        // S^T = K · Q^T : lane holds 32 keys for its q = l&31
        f32x16 st0 = {}, st1 = {};
        __builtin_amdgcn_s_setprio(1);
#pragma unroll
        for (int dc = 0; dc < 4; ++dc) {
            s16x8 kf0 = *(const s16x8*)&lds_k[half][q31][dc*16 + G*8];
            s16x8 kf1 = *(const s16x8*)&lds_k[half][32 + q31][dc*16 + G*8];
            st0 = __builtin_amdgcn_mfma_f32_32x32x16_bf16(kf0, qf[dc], st0, 0,0,0);
            st1 = __builtin_amdgcn_mfma_f32_32x32x16_bf16(kf1, qf[dc], st1, 0,0,0);
        }
        __builtin_amdgcn_s_setprio(0);

        // max-free exp2 softmax (LN-bounded inputs; f32 cannot overflow)
        float c0 = 0.f, c1 = 0.f, c2 = 0.f, c3 = 0.f;
#pragma unroll
        for (int r = 0; r < 16; r += 4) {
            st0[r]   = exp2f(st0[r]);   c0 += st0[r];
            st0[r+1] = exp2f(st0[r+1]); c1 += st0[r+1];
            st0[r+2] = exp2f(st0[r+2]); c2 += st0[r+2];
            st0[r+3] = exp2f(st0[r+3]); c3 += st0[r+3];
            st1[r]   = exp2f(st1[r]);   c0 += st1[r];
            st1[r+1] = exp2f(st1[r+1]); c1 += st1[r+1];
            st1[r+2] = exp2f(st1[r+2]); c2 += st1[r+2];
            st1[r+3] = exp2f(st1[r+3]); c3 += st1[r+3];
        }
        l_run += (c0 + c1) + (c2 + c3);

        // O += P @ V  (P packed to bf16 in-register, permlane32_swap exchange)
        __builtin_amdgcn_s_setprio(1);
        PV_STEP(st0, 0, 0);
        PV_STEP(st0, 1, 16);
        PV_STEP(st1, 0, 32);
        PV_STEP(st1, 1, 48);
        __builtin_amdgcn_s_setprio(0);
    }

    l_run += __shfl_xor(l_run, 32);   // cross-G sum: l(q) complete per lane

    // merge kv-halves (no max tracking -> plain add) and write
    __syncthreads();
    float* mb = (float*)&lds_k[0][0][0];   // 16 KB
    float* ml = (float*)&lds_v[0][0][0];
    if (half == 1) {
#pragma unroll
        for (int r = 0; r < 16; ++r) {
            mb[((wid&1)*2 + 0)*1024 + r*64 + l] = o0[r];
            mb[((wid&1)*2 + 1)*1024 + r*64 + l] = o1[r];
        }
        ml[(wid&1)*64 + l] = l_run;
    }
    __syncthreads();
    if (half == 0) {
        float lt = l_run + ml[(wid&1)*64 + l];
        float inv = 1.0f / lt;
        ushort* ob = out + (size_t)b * SEQ * DIM + h * HD;
#pragma unroll
        for (int r = 0; r < 16; ++r) {
            int qr = (r & 3) + 8*(r >> 2) + 4*G;
            float invr = __shfl(inv, qr);
            float v0 = (o0[r] + mb[((wid&1)*2 + 0)*1024 + r*64 + l]) * invr;
            float v1 = (o1[r] + mb[((wid&1)*2 + 1)*1024 + r*64 + l]) * invr;
            int row = q0 + qr;
            ob[(size_t)row * DIM + q31]      = f2bf(v0);
            ob[(size_t)row * DIM + 32 + q31] = f2bf(v1);
        }
    }
}

extern "C" void kernel_launch(void* const* d_in, const int* in_sizes, int n_in,
                              void* d_out, int out_size, void* d_ws, size_t ws_size,
                              hipStream_t stream) {
    const float* x      = (const float*)d_in[0];
    const float* qkv_w  = (const float*)d_in[1];
    const float* proj_w = (const float*)d_in[2];
    const float* proj_b = (const float*)d_in[3];
    const float* ln1_w  = (const float*)d_in[4];
    const float* ln1_b  = (const float*)d_in[5];
    const float* ln2_w  = (const float*)d_in[6];
    const float* ln2_b  = (const float*)d_in[7];
    const float* fc1_w  = (const float*)d_in[8];
    const float* fc1_b  = (const float*)d_in[9];
    const float* fc2_w  = (const float*)d_in[10];
    const float* fc2_b  = (const float*)d_in[11];
    float* outp = (float*)d_out;

    char* ws = (char*)d_ws;
    size_t off = 0;
    auto alloc = [&](size_t bytes) {
        off = (off + 255) & ~(size_t)255;
        void* p = ws + off;
        off += bytes;
        return p;
    };
    ushort* wq   = (ushort*)alloc((size_t)QKVN * DIM * 2);
    ushort* wp   = (ushort*)alloc((size_t)DIM * DIM * 2);
    ushort* w1   = (ushort*)alloc((size_t)HIDDEN * DIM * 2);
    ushort* w2   = (ushort*)alloc((size_t)DIM * HIDDEN * 2);
    ushort* y1   = (ushort*)alloc((size_t)NTOK * DIM * 2);
    ushort* qkvb = (ushort*)alloc((size_t)NTOK * QKVN * 2);
    ushort* ao   = (ushort*)alloc((size_t)NTOK * DIM * 2);
    float*  res  = (float*) alloc((size_t)NTOK * DIM * 4);
    ushort* y2   = (ushort*)alloc((size_t)NTOK * DIM * 2);
    ushort* hb   = (ushort*)alloc((size_t)NTOK * HIDDEN * 2);

    const int n0 = QKVN*DIM/4, n1 = DIM*DIM/4, n2 = HIDDEN*DIM/4, n3 = DIM*HIDDEN/4;
    cvt4_kernel<<<(n0+n1+n2+n3 + 255)/256, 256, 0, stream>>>(
        (const float4*)qkv_w, wq, n0, (const float4*)proj_w, wp, n1,
        (const float4*)fc1_w, w1, n2, (const float4*)fc2_w, w2, n3);

    ln_kernel<<<NTOK/4, 256, 0, stream>>>(x, ln1_w, ln1_b, y1);
    gemm_kernel<0,128><<<dim3(NTOK/128, QKVN/128), 256, 0, stream>>>(y1, wq, nullptr, nullptr, qkvb, NTOK, QKVN, DIM);
    attn_kernel<<<dim3(SEQ/64, BATCH*HEADS), 256, 0, stream>>>(qkvb, ao);
    gemm_kernel<1,64><<<dim3(NTOK/128, DIM/64), 256, 0, stream>>>(ao, wp, proj_b, x, res, NTOK, DIM, DIM);
    ln_kernel<<<NTOK/4, 256, 0, stream>>>(res, ln2_w, ln2_b, y2);
    gemm_kernel<2,128><<<dim3(NTOK/128, HIDDEN/128), 256, 0, stream>>>(y2, w1, fc1_b, nullptr, hb, NTOK, HIDDEN, DIM);
    gemm_kernel<3,64><<<dim3(NTOK/128, DIM/64), 256, 0, stream>>>(hb, w2, fc2_b, nullptr, outp, NTOK, DIM, HIDDEN);
}

// Round 5
// 248.348 us; speedup vs baseline: 1.1710x; 1.1710x over previous
//
#include <hip/hip_runtime.h>
#include <hip/hip_bf16.h>

#define DIM 384
#define HEADS 6
#define HD 64
#define HIDDEN 1536
#define SEQ 4096
#define BATCH 2
#define NTOK (BATCH*SEQ)   // 8192
#define QKVN (3*DIM)       // 1152

typedef __attribute__((ext_vector_type(4))) float f32x4;
typedef __attribute__((ext_vector_type(16))) float f32x16;
typedef __attribute__((ext_vector_type(8))) short s16x8;
typedef __attribute__((ext_vector_type(4))) unsigned int u32x4;

__device__ __forceinline__ ushort f2bf(float f) {
    union { float f; unsigned u; } v; v.f = f;
    unsigned r = v.u + 0x7FFF + ((v.u >> 16) & 1);
    return (ushort)(r >> 16);
}
__device__ __forceinline__ float bf2f(ushort b) {
    union { unsigned u; float f; } v; v.u = ((unsigned)b) << 16;
    return v.f;
}
__device__ __forceinline__ unsigned cvtpk(float lo, float hi) {
    unsigned r;
    asm("v_cvt_pk_bf16_f32 %0, %1, %2" : "=v"(r) : "v"(lo), "v"(hi));
    return r;
}
__device__ __forceinline__ void pl32swap(unsigned& a, unsigned& b) {
    asm volatile("v_permlane32_swap_b32 %0, %1" : "+v"(a), "+v"(b));
}
__device__ __forceinline__ void g2l(const ushort* g, ushort* s) {
    __builtin_amdgcn_global_load_lds((const __attribute__((address_space(1))) void*)g,
                                     (__attribute__((address_space(3))) void*)s, 16, 0, 0);
}

// ---------------- merged weight f32 -> bf16 ----------------
__global__ void cvt4_kernel(const float4* __restrict__ s0, ushort* __restrict__ d0, int n0,
                            const float4* __restrict__ s1, ushort* __restrict__ d1, int n1,
                            const float4* __restrict__ s2, ushort* __restrict__ d2, int n2,
                            const float4* __restrict__ s3, ushort* __restrict__ d3, int n3) {
    int i = blockIdx.x * 256 + threadIdx.x;
    const float4* s; ushort* d; int k = i;
    if (i < n0) { s = s0; d = d0; }
    else { k -= n0; if (k < n1) { s = s1; d = d1; }
        else { k -= n1; if (k < n2) { s = s2; d = d2; }
            else { k -= n2; if (k >= n3) return; s = s3; d = d3; } } }
    float4 v = s[k];
    ushort4 o; o.x = f2bf(v.x); o.y = f2bf(v.y); o.z = f2bf(v.z); o.w = f2bf(v.w);
    *(ushort4*)(d + (size_t)k * 4) = o;
}

// ---------------- LayerNorm (wave per row, 384 cols) ----------------
__global__ __launch_bounds__(256) void ln_kernel(const float* __restrict__ x,
        const float* __restrict__ w, const float* __restrict__ b,
        ushort* __restrict__ y) {
    int l = threadIdx.x & 63;
    int row = blockIdx.x * 4 + (threadIdx.x >> 6);
    const float* xr = x + (size_t)row * DIM;
    float v[6], s = 0.f, s2 = 0.f;
#pragma unroll
    for (int i = 0; i < 6; ++i) { v[i] = xr[l + 64*i]; s += v[i]; s2 += v[i]*v[i]; }
#pragma unroll
    for (int d = 1; d < 64; d <<= 1) { s += __shfl_xor(s, d); s2 += __shfl_xor(s2, d); }
    float mean = s * (1.f/DIM);
    float var  = s2 * (1.f/DIM) - mean*mean;
    float rstd = rsqrtf(var + 1e-5f);
    ushort* yr = y + (size_t)row * DIM;
#pragma unroll
    for (int i = 0; i < 6; ++i) {
        int c = l + 64*i;
        yr[c] = f2bf((v[i]-mean)*rstd*w[c] + b[c]);
    }
}

// ---------------- GEMM: 64xBN tile, BK=64, g2l + XOR-8 swizzle, deep grid ----------------
// LDS[r][chunk s] holds global chunk s^(r&7); rows are 64 elems (8 x 16B chunks).
// Source-side swizzle keeps g2l dest linear (rule: both-sides-or-neither).
template<int EPI, int BN>
__global__ __launch_bounds__(256, 4) void gemm_kernel(
        const ushort* __restrict__ A, const ushort* __restrict__ W,
        const float* __restrict__ bias, const float* __restrict__ resid,
        void* __restrict__ Cout, int M, int N, int K) {
    __shared__ __align__(16) ushort lds_a[64*64];
    __shared__ __align__(16) ushort lds_w[BN*64];
    const int t = threadIdx.x, l = t & 63, wid = t >> 6;
    const int lo = l & 15, lg = l >> 4;
    const int m0 = blockIdx.x * 64, n0 = blockIdx.y * BN;
    constexpr int NI = BN / 32;              // 4 (BN=128) or 2 (BN=64)
    constexpr int WW = BN / 32;              // W g2l rounds per wave
    const int wm = (wid & 1) * 32, wn = (wid >> 1) * (BN / 2);
    f32x4 acc[2][NI] = {};

    const int srow8 = l >> 3;                  // 0..7
    const int schunk = (l & 7) ^ srow8;        // XOR-swizzled source chunk
    // A: wave stages 16 rows (2 g2l); W: wave stages WW*8 rows
    const ushort* gA[2];
    ushort* lA[2];
#pragma unroll
    for (int w = 0; w < 2; ++w) {
        gA[w] = A + (size_t)(m0 + wid*16 + w*8 + srow8) * K + schunk*8;
        lA[w] = &lds_a[(wid*16 + w*8)*64];
    }
    const ushort* gW[WW];
    ushort* lW[WW];
#pragma unroll
    for (int w = 0; w < WW; ++w) {
        gW[w] = W + (size_t)(n0 + wid*(8*WW) + w*8 + srow8) * K + schunk*8;
        lW[w] = &lds_w[(wid*(8*WW) + w*8)*64];
    }

    const int lo7 = lo & 7;
    for (int k0 = 0; k0 < K; k0 += 64) {
        if (k0) __syncthreads();
#pragma unroll
        for (int w = 0; w < 2; ++w)  g2l(gA[w] + k0, lA[w]);
#pragma unroll
        for (int w = 0; w < WW; ++w) g2l(gW[w] + k0, lW[w]);
        __syncthreads();
#pragma unroll
        for (int kk = 0; kk < 2; ++kk) {
            const int ch = ((kk*4 + lg) ^ lo7) * 8;
            s16x8 af[2], bfr[NI];
#pragma unroll
            for (int mi = 0; mi < 2; ++mi)
                af[mi] = *(const s16x8*)&lds_a[(wm + mi*16 + lo)*64 + ch];
#pragma unroll
            for (int ni = 0; ni < NI; ++ni)
                bfr[ni] = *(const s16x8*)&lds_w[(wn + ni*16 + lo)*64 + ch];
#pragma unroll
            for (int mi = 0; mi < 2; ++mi)
#pragma unroll
                for (int ni = 0; ni < NI; ++ni)
                    acc[mi][ni] = __builtin_amdgcn_mfma_f32_16x16x32_bf16(af[mi], bfr[ni], acc[mi][ni], 0,0,0);
        }
    }

#pragma unroll
    for (int mi = 0; mi < 2; ++mi)
#pragma unroll
    for (int ni = 0; ni < NI; ++ni)
#pragma unroll
    for (int r = 0; r < 4; ++r) {
        int row = m0 + wm + mi*16 + lg*4 + r;
        int col = n0 + wn + ni*16 + lo;
        float c = acc[mi][ni][r];
        size_t idx = (size_t)row * N + col;
        if (EPI == 0) {
            ((ushort*)Cout)[idx] = f2bf(c);
        } else if (EPI == 1) {
            ((float*)Cout)[idx] = c + bias[col] + resid[idx];
        } else if (EPI == 2) {
            c += bias[col];
            ((ushort*)Cout)[idx] = f2bf(0.5f * c * (1.f + erff(c * 0.70710678118f)));
        } else {
            ((float*)Cout)[idx] = 2.f * (c + bias[col]);
        }
    }
}

// ---------------- Flash attention: max-free exp2 softmax, MFMA row-sum ----------------
#define PV_STEP(S, MM, CB) do {                                                   \
    unsigned w0 = cvtpk(S[8*MM+0], S[8*MM+1]);                                    \
    unsigned w1 = cvtpk(S[8*MM+2], S[8*MM+3]);                                    \
    unsigned w2 = cvtpk(S[8*MM+4], S[8*MM+5]);                                    \
    unsigned w3 = cvtpk(S[8*MM+6], S[8*MM+7]);                                    \
    pl32swap(w0, w2); pl32swap(w1, w3);                                           \
    u32x4 fw = {w0, w1, w2, w3};                                                  \
    s16x8 pa = __builtin_bit_cast(s16x8, fw);                                     \
    int colb = ((CB) + G*8) ^ swz0;                                               \
    s16x8 vb0 = *(const s16x8*)&lds_v[half][q31][colb];                           \
    s16x8 vb1 = *(const s16x8*)&lds_v[half][32 + q31][colb ^ 32];                 \
    o0 = __builtin_amdgcn_mfma_f32_32x32x16_bf16(pa, vb0, o0, 0,0,0);             \
    o1 = __builtin_amdgcn_mfma_f32_32x32x16_bf16(pa, vb1, o1, 0,0,0);             \
    ol = __builtin_amdgcn_mfma_f32_32x32x16_bf16(pa, vones, ol, 0,0,0);           \
} while (0)

__global__ __launch_bounds__(256, 3) void attn_kernel(const ushort* __restrict__ qkv,
                                                      ushort* __restrict__ out) {
    __shared__ __align__(16) ushort lds_k[2][64][72];
    __shared__ __align__(16) ushort lds_v[2][64][72];
    const int t = threadIdx.x, l = t & 63, wid = t >> 6;
    const int G = l >> 5, q31 = l & 31, half = wid >> 1;
    const int b = blockIdx.y / HEADS, h = blockIdx.y % HEADS;
    const ushort* base = qkv + (size_t)b * SEQ * QKVN + h * HD;
    const int q0 = blockIdx.x * 64 + (wid & 1) * 32;

    // Q fragments pre-scaled by 0.125*log2(e) (exp2 domain)
    const float QSC = 0.1803368801111137f;
    s16x8 qf[4];
#pragma unroll
    for (int dc = 0; dc < 4; ++dc) {
        s16x8 qv = *(const s16x8*)(base + (size_t)(q0 + q31) * QKVN + dc*16 + G*8);
#pragma unroll
        for (int j = 0; j < 8; ++j)
            qv[j] = (short)f2bf(bf2f((ushort)qv[j]) * QSC);
        qf[dc] = qv;
    }
    s16x8 vones;
#pragma unroll
    for (int j = 0; j < 8; ++j) vones[j] = (short)0x3F80;   // bf16 1.0

    f32x16 o0 = {}, o1 = {}, ol = {};

    const int u = t & 127, sa = u >> 3, sc = u & 7;
    const ushort* kbase = base + DIM;
    const ushort* vbase = base + 2*DIM;
    const int key0base = half * (SEQ/2);
    const int swz0 = ((q31 >> 3) & 3) << 3;

    s16x8 kreg[4], vreg[4];
#pragma unroll
    for (int p = 0; p < 4; ++p) {
        kreg[p] = *(const s16x8*)(kbase + (size_t)(key0base + p*16 + sa) * QKVN + sc*8);
        vreg[p] = *(const s16x8*)(vbase + (size_t)(key0base + p*16 + sa) * QKVN + sc*8);
    }

    for (int it = 0; it < 32; ++it) {
        const int key0 = key0base + it*64;
        __syncthreads();   // previous compute done; LDS writable
#pragma unroll
        for (int p = 0; p < 4; ++p) {
            *(s16x8*)&lds_k[half][p*16 + sa][sc*8] = kreg[p];
            const int colp = (p*16 + sa) ^ ((sc & 3) << 3) ^ ((sc >> 2) << 5);
#pragma unroll
            for (int j = 0; j < 8; ++j)
                lds_v[half][sc*8 + j][colp] = (ushort)vreg[p][j];
        }
        __syncthreads();
        if (it < 31) {     // prefetch next K+V tiles into regs
#pragma unroll
            for (int p = 0; p < 4; ++p) {
                kreg[p] = *(const s16x8*)(kbase + (size_t)(key0 + 64 + p*16 + sa) * QKVN + sc*8);
                vreg[p] = *(const s16x8*)(vbase + (size_t)(key0 + 64 + p*16 + sa) * QKVN + sc*8);
            }
        }

        // S^T = K * Q^T
        f32x16 st0 = {}, st1 = {};
        __builtin_amdgcn_s_setprio(1);
#pragma unroll
        for (int dc = 0; dc < 4; ++dc) {
            s16x8 kf0 = *(const s16x8*)&lds_k[half][q31][dc*16 + G*8];
            s16x8 kf1 = *(const s16x8*)&lds_k[half][32 + q31][dc*16 + G*8];
            st0 = __builtin_amdgcn_mfma_f32_32x32x16_bf16(kf0, qf[dc], st0, 0,0,0);
            st1 = __builtin_amdgcn_mfma_f32_32x32x16_bf16(kf1, qf[dc], st1, 0,0,0);
        }
        __builtin_amdgcn_s_setprio(0);

        // max-free exp2 (LN-bounded; f32 cannot overflow); sum comes from ones-MFMA
#pragma unroll
        for (int r = 0; r < 16; ++r) {
            st0[r] = exp2f(st0[r]);
            st1[r] = exp2f(st1[r]);
        }

        __builtin_amdgcn_s_setprio(1);
        PV_STEP(st0, 0, 0);
        PV_STEP(st0, 1, 16);
        PV_STEP(st1, 0, 32);
        PV_STEP(st1, 1, 48);
        __builtin_amdgcn_s_setprio(0);
    }

    // merge kv-halves (plain add) and write; l per row r direct from ol
    __syncthreads();
    float* mb = (float*)&lds_k[0][0][0];   // 16 KB: [pair*2+dt][r][lane]
    float* ml = (float*)&lds_v[0][0][0];   // 8 KB:  [pair][r][lane]
    if (half == 1) {
#pragma unroll
        for (int r = 0; r < 16; ++r) {
            mb[((wid&1)*2 + 0)*1024 + r*64 + l] = o0[r];
            mb[((wid&1)*2 + 1)*1024 + r*64 + l] = o1[r];
            ml[(wid&1)*1024 + r*64 + l] = ol[r];
        }
    }
    __syncthreads();
    if (half == 0) {
        ushort* ob = out + (size_t)b * SEQ * DIM + h * HD;
#pragma unroll
        for (int r = 0; r < 16; ++r) {
            float invr = 1.0f / (ol[r] + ml[(wid&1)*1024 + r*64 + l]);
            float v0 = (o0[r] + mb[((wid&1)*2 + 0)*1024 + r*64 + l]) * invr;
            float v1 = (o1[r] + mb[((wid&1)*2 + 1)*1024 + r*64 + l]) * invr;
            int qr = (r & 3) + 8*(r >> 2) + 4*G;
            int row = q0 + qr;
            ob[(size_t)row * DIM + q31]      = f2bf(v0);
            ob[(size_t)row * DIM + 32 + q31] = f2bf(v1);
        }
    }
}

extern "C" void kernel_launch(void* const* d_in, const int* in_sizes, int n_in,
                              void* d_out, int out_size, void* d_ws, size_t ws_size,
                              hipStream_t stream) {
    const float* x      = (const float*)d_in[0];
    const float* qkv_w  = (const float*)d_in[1];
    const float* proj_w = (const float*)d_in[2];
    const float* proj_b = (const float*)d_in[3];
    const float* ln1_w  = (const float*)d_in[4];
    const float* ln1_b  = (const float*)d_in[5];
    const float* ln2_w  = (const float*)d_in[6];
    const float* ln2_b  = (const float*)d_in[7];
    const float* fc1_w  = (const float*)d_in[8];
    const float* fc1_b  = (const float*)d_in[9];
    const float* fc2_w  = (const float*)d_in[10];
    const float* fc2_b  = (const float*)d_in[11];
    float* outp = (float*)d_out;

    char* ws = (char*)d_ws;
    size_t off = 0;
    auto alloc = [&](size_t bytes) {
        off = (off + 255) & ~(size_t)255;
        void* p = ws + off;
        off += bytes;
        return p;
    };
    ushort* wq   = (ushort*)alloc((size_t)QKVN * DIM * 2);
    ushort* wp   = (ushort*)alloc((size_t)DIM * DIM * 2);
    ushort* w1   = (ushort*)alloc((size_t)HIDDEN * DIM * 2);
    ushort* w2   = (ushort*)alloc((size_t)DIM * HIDDEN * 2);
    ushort* y1   = (ushort*)alloc((size_t)NTOK * DIM * 2);
    ushort* qkvb = (ushort*)alloc((size_t)NTOK * QKVN * 2);
    ushort* ao   = (ushort*)alloc((size_t)NTOK * DIM * 2);
    float*  res  = (float*) alloc((size_t)NTOK * DIM * 4);
    ushort* y2   = (ushort*)alloc((size_t)NTOK * DIM * 2);
    ushort* hb   = (ushort*)alloc((size_t)NTOK * HIDDEN * 2);

    const int n0 = QKVN*DIM/4, n1 = DIM*DIM/4, n2 = HIDDEN*DIM/4, n3 = DIM*HIDDEN/4;
    cvt4_kernel<<<(n0+n1+n2+n3 + 255)/256, 256, 0, stream>>>(
        (const float4*)qkv_w, wq, n0, (const float4*)proj_w, wp, n1,
        (const float4*)fc1_w, w1, n2, (const float4*)fc2_w, w2, n3);

    ln_kernel<<<NTOK/4, 256, 0, stream>>>(x, ln1_w, ln1_b, y1);
    gemm_kernel<0,128><<<dim3(NTOK/64, QKVN/128), 256, 0, stream>>>(y1, wq, nullptr, nullptr, qkvb, NTOK, QKVN, DIM);
    attn_kernel<<<dim3(SEQ/64, BATCH*HEADS), 256, 0, stream>>>(qkvb, ao);
    gemm_kernel<1,64><<<dim3(NTOK/64, DIM/64), 256, 0, stream>>>(ao, wp, proj_b, x, res, NTOK, DIM, DIM);
    ln_kernel<<<NTOK/4, 256, 0, stream>>>(res, ln2_w, ln2_b, y2);
    gemm_kernel<2,128><<<dim3(NTOK/64, HIDDEN/128), 256, 0, stream>>>(y2, w1, fc1_b, nullptr, hb, NTOK, HIDDEN, DIM);
    gemm_kernel<3,64><<<dim3(NTOK/64, DIM/64), 256, 0, stream>>>(hb, w2, fc2_b, nullptr, outp, NTOK, DIM, HIDDEN);
}